// Round 7
// baseline (959.754 us; speedup 1.0000x reference)
//
#include <hip/hip_runtime.h>
#include <math.h>

// MomentLayerRecurrent — round 7.
// vs round 6: NO LDS staging, NO K-loop barriers. All GEMM operands (W, Q, T1)
// stored in fragment-tiled split-bf16 "TS" format: 16-row x 32-k blocks of
// 512 ushorts ordered lane-major for the mfma_16x16x32 A/B layout (identical
// for both operands). Each fragment = one coalesced per-wave
// global_load_dwordx4 (lane*16B) from L1/L2 directly to registers. r6 evidence:
// LDS pipe needed ~1540 cyc/iter/CU vs MFMA 460, and __syncthreads forced a
// vmcnt(0) drain every iter — both eliminated. Epilogues write T1/Q_next in TS.

#define BB 32
#define NN 512
#define SEQ 8
#define TG 7001

typedef float f32x4 __attribute__((ext_vector_type(4)));
typedef short s16x8 __attribute__((ext_vector_type(8)));

__device__ __forceinline__ unsigned short bf16_rne(float v) {
    unsigned u = __float_as_uint(v);
    u += 0x7FFFu + ((u >> 16) & 1u);
    return (unsigned short)(u >> 16);
}
__device__ __forceinline__ float bf16_f(unsigned short h) {
    return __uint_as_float(((unsigned)h) << 16);
}
__device__ __forceinline__ void split2(float v, unsigned short& h, unsigned short& l) {
    unsigned short hh = bf16_rne(v);
    h = hh;
    l = bf16_rne(v - bf16_f(hh));
}

// TS index (ushort units): block = (r>>4)*16 + (k>>5), lane' = (r&15)|(((k>>3)&3)<<4)
__device__ __forceinline__ size_t ts_idx(int r, int k) {
    return (size_t)(((r >> 4) * 16 + (k >> 5)) * 512 + ((k >> 3) & 3) * 128 + (r & 15) * 8 + (k & 7));
}

__device__ __forceinline__ float interp_tab(const float* __restrict__ tab, float x) {
    float t = (x + 10.0f) * 500.0f;
    t = fminf(fmaxf(t, 0.0f), 7000.0f);
    int i0 = (int)t;
    if (i0 > 6999) i0 = 6999;
    float fr = t - (float)i0;
    float a = tab[i0];
    float b = tab[i0 + 1];
    return a + fr * (b - a);
}

// ---------------- exp precompute (parallel) ----------------------------------
__global__ void k_exp(double* __restrict__ expP, double* __restrict__ expM) {
    int k = blockIdx.x * 256 + threadIdx.x;
    if (k >= TG) return;
    double x = -10.0 + (14.0 / 7000.0) * k;
    expP[k] = exp(x * x);
    expM[k] = exp(-x * x);
}

// ---------------- chained cumtrapz scans, y staged in LDS --------------------
__device__ double blk_exscan(double part, double* wsum) {
    int t = threadIdx.x, lane = t & 63, wid = t >> 6;
    double run = part;
    #pragma unroll
    for (int off = 1; off < 64; off <<= 1) {
        double nv = __shfl_up(run, off);
        if (lane >= off) run += nv;
    }
    if (lane == 63) wsum[wid] = run;
    __syncthreads();
    if (t < 16) {
        double v = wsum[t];
        #pragma unroll
        for (int off = 1; off < 16; off <<= 1) {
            double nv = __shfl_up(v, off);
            if (lane >= off) v += nv;
        }
        wsum[t] = v;
    }
    __syncthreads();
    double base = (wid > 0) ? wsum[wid - 1] : 0.0;
    double ex = base + run - part;
    __syncthreads();
    return ex;
}

__global__ __launch_bounds__(1024)
void k_scan(const double* __restrict__ expP, const double* __restrict__ expM,
            float* __restrict__ GT, float* __restrict__ GI, float* __restrict__ HI) {
    __shared__ double ys[7008];
    __shared__ double wsum[16];
    const int t = threadIdx.x;
    const double dx = 14.0 / 7000.0;
    int k0 = t * 7, k1 = k0 + 7;
    if (k1 > TG) k1 = TG;
    if (k0 > TG) k0 = TG;
    int kls = (k0 < 1) ? 1 : k0;

    for (int k = k0; k < k1; ++k) ys[k] = expM[k];
    __syncthreads();

    double tmp[7];
    // phase 1: I = exp(-100)/20 + cumtrapz(expM); g = expP*I
    {
        double part = 0.0;
        for (int k = kls; k < k1; ++k) part += 0.5 * (ys[k - 1] + ys[k]) * dx;
        double run = blk_exscan(part, wsum) + exp(-100.0) / 20.0;
        int c = 0;
        for (int k = k0; k < k1; ++k) {
            if (k >= 1) run += 0.5 * (ys[k - 1] + ys[k]) * dx;
            tmp[c] = expP[k] * run;
            GT[k] = (float)tmp[c];
            ++c;
        }
        __syncthreads();
        c = 0;
        for (int k = k0; k < k1; ++k) ys[k] = tmp[c++];
        __syncthreads();
    }
    // phase 2: G = cumtrapz(g)
    {
        double part = 0.0;
        for (int k = kls; k < k1; ++k) part += 0.5 * (ys[k - 1] + ys[k]) * dx;
        double run = blk_exscan(part, wsum);
        for (int k = k0; k < k1; ++k) {
            if (k >= 1) run += 0.5 * (ys[k - 1] + ys[k]) * dx;
            GI[k] = (float)run;
        }
        __syncthreads();
    }
    // phase 3: E = cumtrapz(expM * g^2)
    {
        double part = 0.0;
        for (int k = kls; k < k1; ++k) {
            double ya = expM[k - 1] * ys[k - 1] * ys[k - 1];
            double yb = expM[k] * ys[k] * ys[k];
            part += 0.5 * (ya + yb) * dx;
        }
        double run = blk_exscan(part, wsum);
        int c = 0;
        for (int k = k0; k < k1; ++k) {
            if (k >= 1) {
                double ya = expM[k - 1] * ys[k - 1] * ys[k - 1];
                double yb = expM[k] * ys[k] * ys[k];
                run += 0.5 * (ya + yb) * dx;
            }
            tmp[c++] = run;
        }
        __syncthreads();
        c = 0;
        for (int k = k0; k < k1; ++k) ys[k] = tmp[c++];
        __syncthreads();
    }
    // phase 4: H = cumtrapz(expP * E)
    {
        double part = 0.0;
        for (int k = kls; k < k1; ++k)
            part += 0.5 * (expP[k - 1] * ys[k - 1] + expP[k] * ys[k]) * dx;
        double run = blk_exscan(part, wsum);
        for (int k = k0; k < k1; ++k) {
            if (k >= 1) run += 0.5 * (expP[k - 1] * ys[k - 1] + expP[k] * ys[k]) * dx;
            HI[k] = (float)run;
        }
    }
}

// ---------------- split-to-TS kernels ----------------------------------------
__global__ void k_splitW(const float* __restrict__ W,
                         unsigned short* __restrict__ Wh, unsigned short* __restrict__ Wl) {
    int t = blockIdx.x * 256 + threadIdx.x;   // 32768 threads
    int r = t >> 6, c8 = t & 63;
    int k = c8 * 8;
    const float* src = W + (size_t)r * NN + k;
    s16x8 hv, lv;
    #pragma unroll
    for (int q = 0; q < 8; ++q) {
        unsigned short h, l;
        split2(src[q], h, l);
        hv[q] = (short)h; lv[q] = (short)l;
    }
    size_t o = ts_idx(r, k);
    *reinterpret_cast<s16x8*>(Wh + o) = hv;
    *reinterpret_cast<s16x8*>(Wl + o) = lv;
}

__global__ void k_splitQ(const float* __restrict__ rho, const float* __restrict__ s,
                         unsigned short* __restrict__ Qh, unsigned short* __restrict__ Ql) {
    int t = blockIdx.x * 256 + threadIdx.x;   // 32*32768 threads
    int b = t >> 15;
    int rem = t & 32767;
    int r = rem >> 6, c8 = rem & 63;
    int k = c8 * 8;
    const float* src = rho + ((size_t)b * NN + r) * NN + k;
    const float* sb = s + b * NN;
    float si = sb[r];
    s16x8 hv, lv;
    #pragma unroll
    for (int q = 0; q < 8; ++q) {
        float v = src[q] * si * sb[k + q];
        unsigned short h, l;
        split2(v, h, l);
        hv[q] = (short)h; lv[q] = (short)l;
    }
    size_t o = (size_t)b * NN * NN + ts_idx(r, k);
    *reinterpret_cast<s16x8*>(Qh + o) = hv;
    *reinterpret_cast<s16x8*>(Ql + o) = lv;
}

// ---------------- barrier-free TS MFMA GEMM step kernels ---------------------
// 128x128 tile, 4 waves (wave tile 64x64 = 4x4 of 16x16), split-2 bf16
// (3 products). Fragments loaded directly global->VGPR from TS arrays.
// PHASE 0: T1 = W@Q (TS out) + diag(C) atomics into sv_a + balanced u_lin fold.
// PHASE 1: C = T1@W^T, BN+activation prologue; writes Q_next TS; diag blocks
// publish u/s_next and zero sv_b.  PHASE 2: like 1 but fp32 rho out (row-major).
template <int PHASE>
__global__ __launch_bounds__(256, 2)
void gemm_ts(const unsigned short* __restrict__ Ah, const unsigned short* __restrict__ Al,
             long aStride,
             const unsigned short* __restrict__ Bh, const unsigned short* __restrict__ Bl,
             long bStride,
             unsigned short* __restrict__ Oh, unsigned short* __restrict__ Ol,
             float* __restrict__ Of,
             const float* __restrict__ Wf, float* __restrict__ sv_a, float* __restrict__ sv_b,
             const float* __restrict__ u_prev, const float* __restrict__ bvec,
             float* __restrict__ u_lin,
             const float* __restrict__ bn_w, const float* __restrict__ bmv,
             const float* __restrict__ u_e, const float* __restrict__ s_e2,
             const float* __restrict__ GT, const float* __restrict__ GI,
             const float* __restrict__ HI,
             float* __restrict__ u_next, float* __restrict__ s_next) {
    __shared__ float slS[256], chS[256], snS[256];

    const int id = blockIdx.x;
    const int member = (id >> 3) & 3;
    const int g = (id & 7) | ((id >> 5) << 3);
    const int p = g & 3;
    const int b = g >> 2;
    const int xt = (PHASE == 0) ? p : member;   // B-sharers (PHASE0) /
    const int yt = (PHASE == 0) ? member : p;   // A-sharers (PHASE1/2) same XCD
    const int i0 = yt * 128, j0 = xt * 128;
    const int tid = threadIdx.x;
    const int w = tid >> 6, lane = tid & 63;
    const int wqm = w >> 1, wqn = w & 1;

    // ---- prologue ----
    if (PHASE == 0) {
        // balanced u-GEMV: each of the 16 blocks of batch b does 32 rows
        const int tile16 = yt * 4 + xt;
        const int row = tile16 * 32 + (tid >> 3);
        const int seg = tid & 7;
        const float4* wr = (const float4*)(Wf + (size_t)row * NN + seg * 64);
        const float4* ur = (const float4*)(u_prev + b * NN + seg * 64);
        float a0 = 0.f, a1 = 0.f, a2 = 0.f, a3 = 0.f;
        #pragma unroll
        for (int kk = 0; kk < 16; ++kk) {
            float4 wv = wr[kk], uv = ur[kk];
            a0 = fmaf(wv.x, uv.x, a0);
            a1 = fmaf(wv.y, uv.y, a1);
            a2 = fmaf(wv.z, uv.z, a2);
            a3 = fmaf(wv.w, uv.w, a3);
        }
        float au = (a0 + a1) + (a2 + a3);
        au += __shfl_xor(au, 1);
        au += __shfl_xor(au, 2);
        au += __shfl_xor(au, 4);
        if (seg == 0) u_lin[b * NN + row] = au + bvec[row];
    } else {
        // BN stats + activation for this block's 128 rows + 128 cols
        const int ii = (tid < 128) ? (i0 + tid) : (j0 + tid - 128);
        float m = 0.0f;
        for (int bb = 0; bb < BB; ++bb) m += u_lin[bb * NN + ii];
        m *= (1.0f / BB);
        float v = 0.0f;
        for (int bb = 0; bb < BB; ++bb) {
            float d = u_lin[bb * NN + ii] - m;
            v = fmaf(d, d, v);
        }
        v *= (1.0f / BB);
        float f = bn_w[ii] / sqrtf(v + 1e-5f);
        const int idx = b * NN + ii;
        float s_l = sqrtf(fmaxf(sv_a[idx], 0.0f));
        float un = (u_lin[idx] - m) * f + bmv[ii] + u_e[idx];
        float sn = sqrtf(s_l * s_l * f * f + s_e2[idx]);
        const float SQL = 0.22360679774997896f;
        float ss = fmaxf(sn, 1e-6f);
        float inv = 1.0f / (ss * SQL);
        float ubx = fminf(fmaxf((1.0f - un) * inv, -10.0f), 4.0f);
        float lbx = fminf(fmaxf((0.0f - un) * inv, -10.0f), 4.0f);
        float dG = interp_tab(GI, ubx) - interp_tab(GI, lbx);
        float ua = 1.0f / (5.0f + 40.0f * dG);
        float dH = fmaxf(interp_tab(HI, ubx) - interp_tab(HI, lbx), 0.0f);
        float sa = sqrtf(3200.0f * dH * ua * ua * ua);
        float dg2 = interp_tab(GT, ubx) - interp_tab(GT, lbx);
        float ch = ua * ua * 40.0f * dg2 / (SQL * fmaxf(sa, 1e-9f));
        slS[tid] = s_l;
        chS[tid] = ch;
        snS[tid] = sa;
        if (i0 == j0 && tid < 128) {
            u_next[idx] = ua;
            s_next[idx] = sa;
            sv_b[idx] = 0.0f;
        }
        __syncthreads();   // slS/chS/snS visible (only barrier in the kernel)
    }

    // ---- per-wave TS fragment base pointers ----
    const int laneo = lane * 8;   // ushort offset inside a TS block
    const unsigned short* pAh = Ah + (size_t)b * aStride + (size_t)((i0 >> 4) + wqm * 4) * 8192 + laneo;
    const unsigned short* pAl = Al + (size_t)b * aStride + (size_t)((i0 >> 4) + wqm * 4) * 8192 + laneo;
    const unsigned short* pBh = Bh + (size_t)b * bStride + (size_t)((j0 >> 4) + wqn * 4) * 8192 + laneo;
    const unsigned short* pBl = Bl + (size_t)b * bStride + (size_t)((j0 >> 4) + wqn * 4) * 8192 + laneo;

    f32x4 acc[4][4];
    #pragma unroll
    for (int m2 = 0; m2 < 4; ++m2)
        #pragma unroll
        for (int n2 = 0; n2 < 4; ++n2) acc[m2][n2] = (f32x4){0.f, 0.f, 0.f, 0.f};

    // ---- barrier-free K loop: 16 x (16 coalesced frag loads + 48 MFMA) ----
    #pragma unroll 2
    for (int kb = 0; kb < 16; ++kb) {
        const int off = kb * 512;
        s16x8 ahf[4], alf[4], bhf[4], blf[4];
        #pragma unroll
        for (int t = 0; t < 4; ++t) {
            ahf[t] = *reinterpret_cast<const s16x8*>(pAh + t * 8192 + off);
            alf[t] = *reinterpret_cast<const s16x8*>(pAl + t * 8192 + off);
            bhf[t] = *reinterpret_cast<const s16x8*>(pBh + t * 8192 + off);
            blf[t] = *reinterpret_cast<const s16x8*>(pBl + t * 8192 + off);
        }
        #pragma unroll
        for (int m2 = 0; m2 < 4; ++m2)
            #pragma unroll
            for (int n2 = 0; n2 < 4; ++n2) {
                acc[m2][n2] = __builtin_amdgcn_mfma_f32_16x16x32_bf16(ahf[m2], bhf[n2], acc[m2][n2], 0, 0, 0);
                acc[m2][n2] = __builtin_amdgcn_mfma_f32_16x16x32_bf16(ahf[m2], blf[n2], acc[m2][n2], 0, 0, 0);
                acc[m2][n2] = __builtin_amdgcn_mfma_f32_16x16x32_bf16(alf[m2], bhf[n2], acc[m2][n2], 0, 0, 0);
            }
    }

    // ---- epilogue — C/D layout: col = lane&15, row = (lane>>4)*4 + reg ----
    const size_t bofs = (size_t)b * NN * NN;
    const int rb0 = i0 + wqm * 64 + (lane >> 4) * 4;
    const int cb0 = j0 + wqn * 64 + (lane & 15);

    if (PHASE == 0) {
        // diag partials: dp = sum_n acc[m][n][r] * W[row, col_n], xor-reduced
        float dp[16];
        #pragma unroll
        for (int m2 = 0; m2 < 4; ++m2)
            #pragma unroll
            for (int r = 0; r < 4; ++r) {
                int row = rb0 + m2 * 16 + r;
                const float* wrow = Wf + ((size_t)row << 9) + cb0;
                float s = 0.0f;
                #pragma unroll
                for (int n2 = 0; n2 < 4; ++n2) s = fmaf(acc[m2][n2][r], wrow[n2 * 16], s);
                dp[m2 * 4 + r] = s;
            }
        #pragma unroll
        for (int k = 0; k < 16; ++k) {
            #pragma unroll
            for (int off = 1; off < 16; off <<= 1) dp[k] += __shfl_xor(dp[k], off);
        }
        if ((lane & 15) == 0) {
            #pragma unroll
            for (int k = 0; k < 16; ++k) {
                int row = rb0 + (k >> 2) * 16 + (k & 3);
                atomicAdd(&sv_a[b * NN + row], dp[k]);
            }
        }
        // store T1 in TS format
        #pragma unroll
        for (int m2 = 0; m2 < 4; ++m2)
            #pragma unroll
            for (int n2 = 0; n2 < 4; ++n2) {
                int col = cb0 + n2 * 16;
                #pragma unroll
                for (int r = 0; r < 4; ++r) {
                    int row = rb0 + m2 * 16 + r;
                    size_t idx = bofs + ts_idx(row, col);
                    unsigned short h, l;
                    split2(acc[m2][n2][r], h, l);
                    Oh[idx] = h; Ol[idx] = l;
                }
            }
    } else {
        const int lrb = wqm * 64 + (lane >> 4) * 4;
        const int lcb = wqn * 64 + (lane & 15);
        #pragma unroll
        for (int m2 = 0; m2 < 4; ++m2)
            #pragma unroll
            for (int r = 0; r < 4; ++r) {
                const int lr = lrb + m2 * 16 + r;
                const float si = slS[lr], ci = chS[lr], qi = snS[lr];
                const int row = i0 + lr;
                #pragma unroll
                for (int n2 = 0; n2 < 4; ++n2) {
                    const int lc = lcb + n2 * 16;
                    const float sj = slS[128 + lc], cj = chS[128 + lc], qj = snS[128 + lc];
                    const int col = j0 + lc;
                    float denom = si * sj;
                    float rv = (denom > 1e-12f) ? (acc[m2][n2][r] / fmaxf(denom, 1e-12f)) : 0.0f;
                    rv *= ci * cj;
                    if (row == col) rv = 1.0f;
                    if (PHASE == 1) {
                        size_t idx = bofs + ts_idx(row, col);
                        unsigned short h, l;
                        split2(rv * qi * qj, h, l);
                        Oh[idx] = h; Ol[idx] = l;
                    } else {
                        Of[bofs + ((size_t)row << 9) + col] = rv;
                    }
                }
            }
    }
}

// ---------------- external pathway -------------------------------------------
__global__ void k_ext_dots(const float* __restrict__ Wx, const float* __restrict__ bx,
                           const float* __restrict__ ux, const float* __restrict__ sx,
                           float* __restrict__ u_e, float* __restrict__ s_e2) {
    int gw = (blockIdx.x << 2) + (threadIdx.x >> 6);
    int lane = threadIdx.x & 63;
    int b = gw >> 9, i = gw & 511;
    const float* wr = Wx + (size_t)i * NN;
    const float* ub = ux + b * NN;
    const float* sb = sx + b * NN;
    float au = 0.0f, as2 = 0.0f;
    for (int j = lane; j < NN; j += 64) {
        float w = wr[j];
        float s = sb[j];
        au = fmaf(w, ub[j], au);
        as2 = fmaf(w * w, s * s, as2);
    }
    #pragma unroll
    for (int off = 32; off; off >>= 1) {
        au += __shfl_down(au, off);
        as2 += __shfl_down(as2, off);
    }
    if (lane == 0) {
        u_e[b * NN + i] = au + bx[i];
        s_e2[b * NN + i] = as2;
    }
}

__global__ void k_ext_stats(float* __restrict__ u_e, float* __restrict__ s_e2,
                            const float* __restrict__ wmx, const float* __restrict__ bmx) {
    int i = blockIdx.x * blockDim.x + threadIdx.x;
    if (i >= NN) return;
    float m = 0.0f;
    for (int b = 0; b < BB; ++b) m += u_e[b * NN + i];
    m *= (1.0f / BB);
    float v = 0.0f;
    for (int b = 0; b < BB; ++b) {
        float d = u_e[b * NN + i] - m;
        v = fmaf(d, d, v);
    }
    v *= (1.0f / BB);
    float f = wmx[i] / sqrtf(v + 1e-5f);
    float bm = bmx[i];
    for (int b = 0; b < BB; ++b) {
        u_e[b * NN + i] = (u_e[b * NN + i] - m) * f + bm;
        s_e2[b * NN + i] *= f * f;
    }
}

// ---------------- launcher ---------------------------------------------------
extern "C" void kernel_launch(void* const* d_in, const int* in_sizes, int n_in,
                              void* d_out, int out_size, void* d_ws, size_t ws_size,
                              hipStream_t stream) {
    (void)in_sizes; (void)n_in; (void)out_size; (void)ws_size;
    const float* u_in       = (const float*)d_in[0];
    const float* s_in       = (const float*)d_in[1];
    const float* rho_in     = (const float*)d_in[2];
    const float* u_ext      = (const float*)d_in[3];
    const float* s_ext      = (const float*)d_in[4];
    const float* W          = (const float*)d_in[5];
    const float* bvec       = (const float*)d_in[6];
    const float* W_ext      = (const float*)d_in[7];
    const float* b_ext      = (const float*)d_in[8];
    const float* w_mean     = (const float*)d_in[9];
    const float* b_mean     = (const float*)d_in[10];
    const float* w_mean_ext = (const float*)d_in[11];
    const float* b_mean_ext = (const float*)d_in[12];

    float* out_u   = (float*)d_out;
    float* out_s   = out_u + BB * NN;
    float* out_rho = out_s + BB * NN;
    unsigned short* Qh = (unsigned short*)out_rho;            // Q TS lives in
    unsigned short* Ql = Qh + (size_t)BB * NN * NN;           // out_rho region

    char* base = (char*)d_ws;
    size_t off = 0;
    auto alloc = [&](size_t bytes) -> char* {
        char* ptr = base + off;
        off += (bytes + 255) & ~(size_t)255;
        return ptr;
    };
    unsigned short* T1h = (unsigned short*)alloc((size_t)BB * NN * NN * 2);
    unsigned short* T1l = (unsigned short*)alloc((size_t)BB * NN * NN * 2);
    unsigned short* Wh  = (unsigned short*)alloc((size_t)NN * NN * 2);
    unsigned short* Wl  = (unsigned short*)alloc((size_t)NN * NN * 2);
    double* expP = (double*)alloc(TG * 8);
    double* expM = (double*)alloc(TG * 8);
    float* GTt   = (float*)alloc(TG * 4);
    float* GIt   = (float*)alloc(TG * 4);
    float* HIt   = (float*)alloc(TG * 4);
    float* u_e   = (float*)alloc(BB * NN * 4);
    float* s_e2  = (float*)alloc(BB * NN * 4);
    float* uA    = (float*)alloc(BB * NN * 4);
    float* uB2   = (float*)alloc(BB * NN * 4);
    float* sA    = (float*)alloc(BB * NN * 4);
    float* sB2   = (float*)alloc(BB * NN * 4);
    float* u_lin = (float*)alloc(BB * NN * 4);
    float* sv0   = (float*)alloc(BB * NN * 4);
    float* sv1   = (float*)alloc(BB * NN * 4);

    // prologue
    k_exp<<<28, 256, 0, stream>>>(expP, expM);
    k_scan<<<1, 1024, 0, stream>>>(expP, expM, GTt, GIt, HIt);
    k_splitW<<<128, 256, 0, stream>>>(W, Wh, Wl);
    k_splitQ<<<4096, 256, 0, stream>>>(rho_in, s_in, Qh, Ql);
    k_ext_dots<<<BB * NN / 4, 256, 0, stream>>>(W_ext, b_ext, u_ext, s_ext, u_e, s_e2);
    k_ext_stats<<<2, 256, 0, stream>>>(u_e, s_e2, w_mean_ext, b_mean_ext);
    (void)hipMemsetAsync(sv0, 0, BB * NN * 4, stream);  // sv1 zeroed by step 0

    const float* cu = u_in;

    for (int t = 0; t < SEQ; ++t) {
        float* sva = (t & 1) ? sv1 : sv0;
        float* svb = (t & 1) ? sv0 : sv1;
        // T1 = W @ Q (TS), diag atomics into sva, balanced u_lin fold
        gemm_ts<0><<<512, 256, 0, stream>>>(
            Wh, Wl, 0L, Qh, Ql, (long)NN * NN, T1h, T1l, nullptr,
            W, sva, nullptr, cu, bvec, u_lin,
            nullptr, nullptr, nullptr, nullptr, nullptr, nullptr, nullptr,
            nullptr, nullptr);
        float* nu = (t == SEQ - 1) ? out_u : ((t & 1) ? uA : uB2);
        float* ns = (t == SEQ - 1) ? out_s : ((t & 1) ? sA : sB2);
        // C = T1 @ W^T, BN+activation prologue, rho epilogue
        if (t < SEQ - 1) {
            gemm_ts<1><<<512, 256, 0, stream>>>(
                T1h, T1l, (long)NN * NN, Wh, Wl, 0L, Qh, Ql, nullptr,
                nullptr, sva, svb, nullptr, nullptr, u_lin,
                w_mean, b_mean, u_e, s_e2, GTt, GIt, HIt, nu, ns);
        } else {
            gemm_ts<2><<<512, 256, 0, stream>>>(
                T1h, T1l, (long)NN * NN, Wh, Wl, 0L, nullptr, nullptr, out_rho,
                nullptr, sva, svb, nullptr, nullptr, u_lin,
                w_mean, b_mean, u_e, s_e2, GTt, GIt, HIt, nu, ns);
        }
        cu = nu;
    }
}

// Round 8
// 759.386 us; speedup vs baseline: 1.2639x; 1.2639x over previous
//
#include <hip/hip_runtime.h>
#include <math.h>

// MomentLayerRecurrent — round 8.
// vs round 7: the shared ~50µs ceiling across r3-r7 was the epilogue's ~8192
// scattered 2B global_store_short per block (4 x 32B segments per wave-inst).
// Fix: wave-private LDS staging of each 64x64 output quadrant in exact global
// TS byte order, then 1KB-coalesced dwordx4 copy-out (no barrier needed).
// Also: u_lin stored transposed [N x B] so the BN prologue reads float4s.

#define BB 32
#define NN 512
#define SEQ 8
#define TG 7001

typedef float f32x4 __attribute__((ext_vector_type(4)));
typedef short s16x8 __attribute__((ext_vector_type(8)));

__device__ __forceinline__ unsigned short bf16_rne(float v) {
    unsigned u = __float_as_uint(v);
    u += 0x7FFFu + ((u >> 16) & 1u);
    return (unsigned short)(u >> 16);
}
__device__ __forceinline__ float bf16_f(unsigned short h) {
    return __uint_as_float(((unsigned)h) << 16);
}
__device__ __forceinline__ void split2(float v, unsigned short& h, unsigned short& l) {
    unsigned short hh = bf16_rne(v);
    h = hh;
    l = bf16_rne(v - bf16_f(hh));
}

// TS index (ushort units): block = (r>>4)*16 + (k>>5); intra: ((k>>3)&3)*128 + (r&15)*8 + (k&7)
__device__ __forceinline__ size_t ts_idx(int r, int k) {
    return (size_t)(((r >> 4) * 16 + (k >> 5)) * 512 + ((k >> 3) & 3) * 128 + (r & 15) * 8 + (k & 7));
}

__device__ __forceinline__ float interp_tab(const float* __restrict__ tab, float x) {
    float t = (x + 10.0f) * 500.0f;
    t = fminf(fmaxf(t, 0.0f), 7000.0f);
    int i0 = (int)t;
    if (i0 > 6999) i0 = 6999;
    float fr = t - (float)i0;
    float a = tab[i0];
    float b = tab[i0 + 1];
    return a + fr * (b - a);
}

// ---------------- exp precompute (parallel) ----------------------------------
__global__ void k_exp(double* __restrict__ expP, double* __restrict__ expM) {
    int k = blockIdx.x * 256 + threadIdx.x;
    if (k >= TG) return;
    double x = -10.0 + (14.0 / 7000.0) * k;
    expP[k] = exp(x * x);
    expM[k] = exp(-x * x);
}

// ---------------- chained cumtrapz scans, y staged in LDS --------------------
__device__ double blk_exscan(double part, double* wsum) {
    int t = threadIdx.x, lane = t & 63, wid = t >> 6;
    double run = part;
    #pragma unroll
    for (int off = 1; off < 64; off <<= 1) {
        double nv = __shfl_up(run, off);
        if (lane >= off) run += nv;
    }
    if (lane == 63) wsum[wid] = run;
    __syncthreads();
    if (t < 16) {
        double v = wsum[t];
        #pragma unroll
        for (int off = 1; off < 16; off <<= 1) {
            double nv = __shfl_up(v, off);
            if (lane >= off) v += nv;
        }
        wsum[t] = v;
    }
    __syncthreads();
    double base = (wid > 0) ? wsum[wid - 1] : 0.0;
    double ex = base + run - part;
    __syncthreads();
    return ex;
}

__global__ __launch_bounds__(1024)
void k_scan(const double* __restrict__ expP, const double* __restrict__ expM,
            float* __restrict__ GT, float* __restrict__ GI, float* __restrict__ HI) {
    __shared__ double ys[7008];
    __shared__ double wsum[16];
    const int t = threadIdx.x;
    const double dx = 14.0 / 7000.0;
    int k0 = t * 7, k1 = k0 + 7;
    if (k1 > TG) k1 = TG;
    if (k0 > TG) k0 = TG;
    int kls = (k0 < 1) ? 1 : k0;

    for (int k = k0; k < k1; ++k) ys[k] = expM[k];
    __syncthreads();

    double tmp[7];
    {
        double part = 0.0;
        for (int k = kls; k < k1; ++k) part += 0.5 * (ys[k - 1] + ys[k]) * dx;
        double run = blk_exscan(part, wsum) + exp(-100.0) / 20.0;
        int c = 0;
        for (int k = k0; k < k1; ++k) {
            if (k >= 1) run += 0.5 * (ys[k - 1] + ys[k]) * dx;
            tmp[c] = expP[k] * run;
            GT[k] = (float)tmp[c];
            ++c;
        }
        __syncthreads();
        c = 0;
        for (int k = k0; k < k1; ++k) ys[k] = tmp[c++];
        __syncthreads();
    }
    {
        double part = 0.0;
        for (int k = kls; k < k1; ++k) part += 0.5 * (ys[k - 1] + ys[k]) * dx;
        double run = blk_exscan(part, wsum);
        for (int k = k0; k < k1; ++k) {
            if (k >= 1) run += 0.5 * (ys[k - 1] + ys[k]) * dx;
            GI[k] = (float)run;
        }
        __syncthreads();
    }
    {
        double part = 0.0;
        for (int k = kls; k < k1; ++k) {
            double ya = expM[k - 1] * ys[k - 1] * ys[k - 1];
            double yb = expM[k] * ys[k] * ys[k];
            part += 0.5 * (ya + yb) * dx;
        }
        double run = blk_exscan(part, wsum);
        int c = 0;
        for (int k = k0; k < k1; ++k) {
            if (k >= 1) {
                double ya = expM[k - 1] * ys[k - 1] * ys[k - 1];
                double yb = expM[k] * ys[k] * ys[k];
                run += 0.5 * (ya + yb) * dx;
            }
            tmp[c++] = run;
        }
        __syncthreads();
        c = 0;
        for (int k = k0; k < k1; ++k) ys[k] = tmp[c++];
        __syncthreads();
    }
    {
        double part = 0.0;
        for (int k = kls; k < k1; ++k)
            part += 0.5 * (expP[k - 1] * ys[k - 1] + expP[k] * ys[k]) * dx;
        double run = blk_exscan(part, wsum);
        for (int k = k0; k < k1; ++k) {
            if (k >= 1) run += 0.5 * (expP[k - 1] * ys[k - 1] + expP[k] * ys[k]) * dx;
            HI[k] = (float)run;
        }
    }
}

// ---------------- split-to-TS kernels ----------------------------------------
__global__ void k_splitW(const float* __restrict__ W,
                         unsigned short* __restrict__ Wh, unsigned short* __restrict__ Wl) {
    int t = blockIdx.x * 256 + threadIdx.x;
    int r = t >> 6, c8 = t & 63;
    int k = c8 * 8;
    const float* src = W + (size_t)r * NN + k;
    s16x8 hv, lv;
    #pragma unroll
    for (int q = 0; q < 8; ++q) {
        unsigned short h, l;
        split2(src[q], h, l);
        hv[q] = (short)h; lv[q] = (short)l;
    }
    size_t o = ts_idx(r, k);
    *reinterpret_cast<s16x8*>(Wh + o) = hv;
    *reinterpret_cast<s16x8*>(Wl + o) = lv;
}

__global__ void k_splitQ(const float* __restrict__ rho, const float* __restrict__ s,
                         unsigned short* __restrict__ Qh, unsigned short* __restrict__ Ql) {
    int t = blockIdx.x * 256 + threadIdx.x;
    int b = t >> 15;
    int rem = t & 32767;
    int r = rem >> 6, c8 = rem & 63;
    int k = c8 * 8;
    const float* src = rho + ((size_t)b * NN + r) * NN + k;
    const float* sb = s + b * NN;
    float si = sb[r];
    s16x8 hv, lv;
    #pragma unroll
    for (int q = 0; q < 8; ++q) {
        float v = src[q] * si * sb[k + q];
        unsigned short h, l;
        split2(v, h, l);
        hv[q] = (short)h; lv[q] = (short)l;
    }
    size_t o = (size_t)b * NN * NN + ts_idx(r, k);
    *reinterpret_cast<s16x8*>(Qh + o) = hv;
    *reinterpret_cast<s16x8*>(Ql + o) = lv;
}

// ---------------- barrier-free TS MFMA GEMM with coalesced epilogue ----------
template <int PHASE>
__global__ __launch_bounds__(256, 2)
void gemm_ts(const unsigned short* __restrict__ Ah, const unsigned short* __restrict__ Al,
             long aStride,
             const unsigned short* __restrict__ Bh, const unsigned short* __restrict__ Bl,
             long bStride,
             unsigned short* __restrict__ Oh, unsigned short* __restrict__ Ol,
             float* __restrict__ Of,
             const float* __restrict__ Wf, float* __restrict__ sv_a, float* __restrict__ sv_b,
             const float* __restrict__ u_prev, const float* __restrict__ bvec,
             float* __restrict__ u_linT,
             const float* __restrict__ bn_w, const float* __restrict__ bmv,
             const float* __restrict__ u_e, const float* __restrict__ s_e2,
             const float* __restrict__ GT, const float* __restrict__ GI,
             const float* __restrict__ HI,
             float* __restrict__ u_next, float* __restrict__ s_next) {
    __shared__ __align__(16) unsigned short stg[4 * 8192];   // 64 KB staging
    __shared__ float slS[256], chS[256], snS[256];

    const int id = blockIdx.x;
    const int member = (id >> 3) & 3;
    const int g = (id & 7) | ((id >> 5) << 3);
    const int p = g & 3;
    const int b = g >> 2;
    const int xt = (PHASE == 0) ? p : member;
    const int yt = (PHASE == 0) ? member : p;
    const int i0 = yt * 128, j0 = xt * 128;
    const int tid = threadIdx.x;
    const int w = tid >> 6, lane = tid & 63;
    const int wqm = w >> 1, wqn = w & 1;

    // ---- prologue ----
    if (PHASE == 0) {
        const int tile16 = yt * 4 + xt;
        const int row = tile16 * 32 + (tid >> 3);
        const int seg = tid & 7;
        const float4* wr = (const float4*)(Wf + (size_t)row * NN + seg * 64);
        const float4* ur = (const float4*)(u_prev + b * NN + seg * 64);
        float a0 = 0.f, a1 = 0.f, a2 = 0.f, a3 = 0.f;
        #pragma unroll
        for (int kk = 0; kk < 16; ++kk) {
            float4 wv = wr[kk], uv = ur[kk];
            a0 = fmaf(wv.x, uv.x, a0);
            a1 = fmaf(wv.y, uv.y, a1);
            a2 = fmaf(wv.z, uv.z, a2);
            a3 = fmaf(wv.w, uv.w, a3);
        }
        float au = (a0 + a1) + (a2 + a3);
        au += __shfl_xor(au, 1);
        au += __shfl_xor(au, 2);
        au += __shfl_xor(au, 4);
        if (seg == 0) u_linT[row * BB + b] = au + bvec[row];
    } else {
        // BN stats + activation; u_linT is [N x B] -> contiguous float4 reads
        const int ii = (tid < 128) ? (i0 + tid) : (j0 + tid - 128);
        float vb[32];
        {
            const float4* ul = (const float4*)(u_linT + (size_t)ii * BB);
            #pragma unroll
            for (int q = 0; q < 8; ++q) {
                float4 t4 = ul[q];
                vb[q * 4 + 0] = t4.x; vb[q * 4 + 1] = t4.y;
                vb[q * 4 + 2] = t4.z; vb[q * 4 + 3] = t4.w;
            }
        }
        float m = 0.0f;
        #pragma unroll
        for (int bb = 0; bb < BB; ++bb) m += vb[bb];
        m *= (1.0f / BB);
        float v = 0.0f;
        #pragma unroll
        for (int bb = 0; bb < BB; ++bb) {
            float d = vb[bb] - m;
            v = fmaf(d, d, v);
        }
        v *= (1.0f / BB);
        float f = bn_w[ii] / sqrtf(v + 1e-5f);
        const int idx = b * NN + ii;
        float s_l = sqrtf(fmaxf(sv_a[idx], 0.0f));
        float un = (vb[b] - m) * f + bmv[ii] + u_e[idx];
        float sn = sqrtf(s_l * s_l * f * f + s_e2[idx]);
        const float SQL = 0.22360679774997896f;
        float ss = fmaxf(sn, 1e-6f);
        float inv = 1.0f / (ss * SQL);
        float ubx = fminf(fmaxf((1.0f - un) * inv, -10.0f), 4.0f);
        float lbx = fminf(fmaxf((0.0f - un) * inv, -10.0f), 4.0f);
        float dG = interp_tab(GI, ubx) - interp_tab(GI, lbx);
        float ua = 1.0f / (5.0f + 40.0f * dG);
        float dH = fmaxf(interp_tab(HI, ubx) - interp_tab(HI, lbx), 0.0f);
        float sa = sqrtf(3200.0f * dH * ua * ua * ua);
        float dg2 = interp_tab(GT, ubx) - interp_tab(GT, lbx);
        float ch = ua * ua * 40.0f * dg2 / (SQL * fmaxf(sa, 1e-9f));
        slS[tid] = s_l;
        chS[tid] = ch;
        snS[tid] = sa;
        if (i0 == j0 && tid < 128) {
            u_next[idx] = ua;
            s_next[idx] = sa;
            sv_b[idx] = 0.0f;
        }
        __syncthreads();   // slS/chS/snS visible (only barrier in the kernel)
    }

    // ---- per-wave TS fragment base pointers ----
    const int laneo = lane * 8;
    const unsigned short* pAh = Ah + (size_t)b * aStride + (size_t)((i0 >> 4) + wqm * 4) * 8192 + laneo;
    const unsigned short* pAl = Al + (size_t)b * aStride + (size_t)((i0 >> 4) + wqm * 4) * 8192 + laneo;
    const unsigned short* pBh = Bh + (size_t)b * bStride + (size_t)((j0 >> 4) + wqn * 4) * 8192 + laneo;
    const unsigned short* pBl = Bl + (size_t)b * bStride + (size_t)((j0 >> 4) + wqn * 4) * 8192 + laneo;

    f32x4 acc[4][4];
    #pragma unroll
    for (int m2 = 0; m2 < 4; ++m2)
        #pragma unroll
        for (int n2 = 0; n2 < 4; ++n2) acc[m2][n2] = (f32x4){0.f, 0.f, 0.f, 0.f};

    // ---- barrier-free K loop ----
    #pragma unroll 2
    for (int kb = 0; kb < 16; ++kb) {
        const int off = kb * 512;
        s16x8 ahf[4], alf[4], bhf[4], blf[4];
        #pragma unroll
        for (int t = 0; t < 4; ++t) {
            ahf[t] = *reinterpret_cast<const s16x8*>(pAh + t * 8192 + off);
            alf[t] = *reinterpret_cast<const s16x8*>(pAl + t * 8192 + off);
            bhf[t] = *reinterpret_cast<const s16x8*>(pBh + t * 8192 + off);
            blf[t] = *reinterpret_cast<const s16x8*>(pBl + t * 8192 + off);
        }
        #pragma unroll
        for (int m2 = 0; m2 < 4; ++m2)
            #pragma unroll
            for (int n2 = 0; n2 < 4; ++n2) {
                acc[m2][n2] = __builtin_amdgcn_mfma_f32_16x16x32_bf16(ahf[m2], bhf[n2], acc[m2][n2], 0, 0, 0);
                acc[m2][n2] = __builtin_amdgcn_mfma_f32_16x16x32_bf16(ahf[m2], blf[n2], acc[m2][n2], 0, 0, 0);
                acc[m2][n2] = __builtin_amdgcn_mfma_f32_16x16x32_bf16(alf[m2], bhf[n2], acc[m2][n2], 0, 0, 0);
            }
    }

    // ---- epilogue — C/D layout: col = lane&15, row = (lane>>4)*4 + reg ----
    const size_t bofs = (size_t)b * NN * NN;
    const int rb0 = i0 + wqm * 64 + (lane >> 4) * 4;
    const int cb0 = j0 + wqn * 64 + (lane & 15);

    if (PHASE == 0) {
        // diag partials: dp = sum_n acc[m][n][r] * W[row, col_n], xor-reduced
        float dp[16];
        #pragma unroll
        for (int m2 = 0; m2 < 4; ++m2)
            #pragma unroll
            for (int r = 0; r < 4; ++r) {
                int row = rb0 + m2 * 16 + r;
                const float* wrow = Wf + ((size_t)row << 9) + cb0;
                float s = 0.0f;
                #pragma unroll
                for (int n2 = 0; n2 < 4; ++n2) s = fmaf(acc[m2][n2][r], wrow[n2 * 16], s);
                dp[m2 * 4 + r] = s;
            }
        #pragma unroll
        for (int k = 0; k < 16; ++k) {
            #pragma unroll
            for (int off = 1; off < 16; off <<= 1) dp[k] += __shfl_xor(dp[k], off);
        }
        if ((lane & 15) == 0) {
            #pragma unroll
            for (int k = 0; k < 16; ++k) {
                int row = rb0 + (k >> 2) * 16 + (k & 3);
                atomicAdd(&sv_a[b * NN + row], dp[k]);
            }
        }
    }

    if (PHASE == 2) {
        // fp32 rho, staged row-major in wave-private LDS then 1KB stores
        float* fS = (float*)stg + w * 4096;
        const int lcf = ((lane >> 4) << 8) + (lane & 15);
        #pragma unroll
        for (int m2 = 0; m2 < 4; ++m2)
            #pragma unroll
            for (int r = 0; r < 4; ++r) {
                const int lr = m2 * 16 + (lane >> 4) * 4 + r;
                const float si = slS[wqm * 64 + lr], ci = chS[wqm * 64 + lr];
                const int row = i0 + wqm * 64 + lr;
                #pragma unroll
                for (int n2 = 0; n2 < 4; ++n2) {
                    const int lc = wqn * 64 + n2 * 16 + (lane & 15);
                    const float sj = slS[128 + lc], cj = chS[128 + lc];
                    const int col = j0 + lc;
                    float denom = si * sj;
                    float rv = (denom > 1e-12f) ? (acc[m2][n2][r] / fmaxf(denom, 1e-12f)) : 0.0f;
                    rv *= ci * cj;
                    if (row == col) rv = 1.0f;
                    fS[lcf + m2 * 1024 + r * 64 + n2 * 16] = rv;
                }
            }
        #pragma unroll
        for (int inst = 0; inst < 16; ++inst) {
            const int row = i0 + wqm * 64 + inst * 4 + (lane >> 4);
            const int col = j0 + wqn * 64 + (lane & 15) * 4;
            *reinterpret_cast<f32x4*>(Of + bofs + ((size_t)row << 9) + col) =
                *reinterpret_cast<const f32x4*>(fS + inst * 256 + (lane >> 4) * 64 + (lane & 15) * 4);
        }
    } else {
        // split-bf16 output staged in wave-private LDS in global TS byte order
        unsigned short* hiS = stg + w * 8192;
        unsigned short* loS = hiS + 4096;
        const int laneconst = (((lane & 15) >> 3) << 7) + ((lane >> 4) << 5) + (lane & 7);
        #pragma unroll
        for (int m2 = 0; m2 < 4; ++m2)
            #pragma unroll
            for (int n2 = 0; n2 < 4; ++n2) {
                const int base = laneconst + m2 * 1024 + (n2 >> 1) * 512 + (n2 & 1) * 256;
                #pragma unroll
                for (int r = 0; r < 4; ++r) {
                    float v;
                    if (PHASE == 0) {
                        v = acc[m2][n2][r];
                    } else {
                        const int lr = wqm * 64 + m2 * 16 + (lane >> 4) * 4 + r;
                        const int lc = wqn * 64 + n2 * 16 + (lane & 15);
                        const float si = slS[lr], ci = chS[lr], qi = snS[lr];
                        const float sj = slS[128 + lc], cj = chS[128 + lc], qj = snS[128 + lc];
                        float denom = si * sj;
                        float rv = (denom > 1e-12f) ? (acc[m2][n2][r] / fmaxf(denom, 1e-12f)) : 0.0f;
                        rv *= ci * cj;
                        if (i0 + lr == j0 + lc) rv = 1.0f;
                        v = rv * qi * qj;
                    }
                    unsigned short h, l;
                    split2(v, h, l);
                    hiS[base + r * 8] = h;
                    loS[base + r * 8] = l;
                }
            }
        // wave-private copy-out: 8 TS blocks x (hi+lo), 1KB coalesced each
        #pragma unroll
        for (int lb = 0; lb < 8; ++lb) {
            const int gb = ((i0 >> 4) + wqm * 4 + (lb >> 1)) * 16 + (j0 >> 5) + wqn * 2 + (lb & 1);
            *reinterpret_cast<s16x8*>(Oh + bofs + (size_t)gb * 512 + laneo) =
                *reinterpret_cast<const s16x8*>(hiS + lb * 512 + laneo);
            *reinterpret_cast<s16x8*>(Ol + bofs + (size_t)gb * 512 + laneo) =
                *reinterpret_cast<const s16x8*>(loS + lb * 512 + laneo);
        }
    }
}

// ---------------- external pathway -------------------------------------------
__global__ void k_ext_dots(const float* __restrict__ Wx, const float* __restrict__ bx,
                           const float* __restrict__ ux, const float* __restrict__ sx,
                           float* __restrict__ u_e, float* __restrict__ s_e2) {
    int gw = (blockIdx.x << 2) + (threadIdx.x >> 6);
    int lane = threadIdx.x & 63;
    int b = gw >> 9, i = gw & 511;
    const float* wr = Wx + (size_t)i * NN;
    const float* ub = ux + b * NN;
    const float* sb = sx + b * NN;
    float au = 0.0f, as2 = 0.0f;
    for (int j = lane; j < NN; j += 64) {
        float w = wr[j];
        float s = sb[j];
        au = fmaf(w, ub[j], au);
        as2 = fmaf(w * w, s * s, as2);
    }
    #pragma unroll
    for (int off = 32; off; off >>= 1) {
        au += __shfl_down(au, off);
        as2 += __shfl_down(as2, off);
    }
    if (lane == 0) {
        u_e[b * NN + i] = au + bx[i];
        s_e2[b * NN + i] = as2;
    }
}

__global__ void k_ext_stats(float* __restrict__ u_e, float* __restrict__ s_e2,
                            const float* __restrict__ wmx, const float* __restrict__ bmx) {
    int i = blockIdx.x * blockDim.x + threadIdx.x;
    if (i >= NN) return;
    float m = 0.0f;
    for (int b = 0; b < BB; ++b) m += u_e[b * NN + i];
    m *= (1.0f / BB);
    float v = 0.0f;
    for (int b = 0; b < BB; ++b) {
        float d = u_e[b * NN + i] - m;
        v = fmaf(d, d, v);
    }
    v *= (1.0f / BB);
    float f = wmx[i] / sqrtf(v + 1e-5f);
    float bm = bmx[i];
    for (int b = 0; b < BB; ++b) {
        u_e[b * NN + i] = (u_e[b * NN + i] - m) * f + bm;
        s_e2[b * NN + i] *= f * f;
    }
}

// ---------------- launcher ---------------------------------------------------
extern "C" void kernel_launch(void* const* d_in, const int* in_sizes, int n_in,
                              void* d_out, int out_size, void* d_ws, size_t ws_size,
                              hipStream_t stream) {
    (void)in_sizes; (void)n_in; (void)out_size; (void)ws_size;
    const float* u_in       = (const float*)d_in[0];
    const float* s_in       = (const float*)d_in[1];
    const float* rho_in     = (const float*)d_in[2];
    const float* u_ext      = (const float*)d_in[3];
    const float* s_ext      = (const float*)d_in[4];
    const float* W          = (const float*)d_in[5];
    const float* bvec       = (const float*)d_in[6];
    const float* W_ext      = (const float*)d_in[7];
    const float* b_ext      = (const float*)d_in[8];
    const float* w_mean     = (const float*)d_in[9];
    const float* b_mean     = (const float*)d_in[10];
    const float* w_mean_ext = (const float*)d_in[11];
    const float* b_mean_ext = (const float*)d_in[12];

    float* out_u   = (float*)d_out;
    float* out_s   = out_u + BB * NN;
    float* out_rho = out_s + BB * NN;
    unsigned short* Qh = (unsigned short*)out_rho;
    unsigned short* Ql = Qh + (size_t)BB * NN * NN;

    char* base = (char*)d_ws;
    size_t off = 0;
    auto alloc = [&](size_t bytes) -> char* {
        char* ptr = base + off;
        off += (bytes + 255) & ~(size_t)255;
        return ptr;
    };
    unsigned short* T1h = (unsigned short*)alloc((size_t)BB * NN * NN * 2);
    unsigned short* T1l = (unsigned short*)alloc((size_t)BB * NN * NN * 2);
    unsigned short* Wh  = (unsigned short*)alloc((size_t)NN * NN * 2);
    unsigned short* Wl  = (unsigned short*)alloc((size_t)NN * NN * 2);
    double* expP = (double*)alloc(TG * 8);
    double* expM = (double*)alloc(TG * 8);
    float* GTt   = (float*)alloc(TG * 4);
    float* GIt   = (float*)alloc(TG * 4);
    float* HIt   = (float*)alloc(TG * 4);
    float* u_e   = (float*)alloc(BB * NN * 4);
    float* s_e2  = (float*)alloc(BB * NN * 4);
    float* uA    = (float*)alloc(BB * NN * 4);
    float* uB2   = (float*)alloc(BB * NN * 4);
    float* sA    = (float*)alloc(BB * NN * 4);
    float* sB2   = (float*)alloc(BB * NN * 4);
    float* u_linT = (float*)alloc(BB * NN * 4);
    float* sv0   = (float*)alloc(BB * NN * 4);
    float* sv1   = (float*)alloc(BB * NN * 4);

    // prologue
    k_exp<<<28, 256, 0, stream>>>(expP, expM);
    k_scan<<<1, 1024, 0, stream>>>(expP, expM, GTt, GIt, HIt);
    k_splitW<<<128, 256, 0, stream>>>(W, Wh, Wl);
    k_splitQ<<<4096, 256, 0, stream>>>(rho_in, s_in, Qh, Ql);
    k_ext_dots<<<BB * NN / 4, 256, 0, stream>>>(W_ext, b_ext, u_ext, s_ext, u_e, s_e2);
    k_ext_stats<<<2, 256, 0, stream>>>(u_e, s_e2, w_mean_ext, b_mean_ext);
    (void)hipMemsetAsync(sv0, 0, BB * NN * 4, stream);  // sv1 zeroed by step 0

    const float* cu = u_in;

    for (int t = 0; t < SEQ; ++t) {
        float* sva = (t & 1) ? sv1 : sv0;
        float* svb = (t & 1) ? sv0 : sv1;
        // T1 = W @ Q (TS), diag atomics into sva, balanced u_lin fold
        gemm_ts<0><<<512, 256, 0, stream>>>(
            Wh, Wl, 0L, Qh, Ql, (long)NN * NN, T1h, T1l, nullptr,
            W, sva, nullptr, cu, bvec, u_linT,
            nullptr, nullptr, nullptr, nullptr, nullptr, nullptr, nullptr,
            nullptr, nullptr);
        float* nu = (t == SEQ - 1) ? out_u : ((t & 1) ? uA : uB2);
        float* ns = (t == SEQ - 1) ? out_s : ((t & 1) ? sA : sB2);
        // C = T1 @ W^T, BN+activation prologue, rho epilogue
        if (t < SEQ - 1) {
            gemm_ts<1><<<512, 256, 0, stream>>>(
                T1h, T1l, (long)NN * NN, Wh, Wl, 0L, Qh, Ql, nullptr,
                nullptr, sva, svb, nullptr, nullptr, u_linT,
                w_mean, b_mean, u_e, s_e2, GTt, GIt, HIt, nu, ns);
        } else {
            gemm_ts<2><<<512, 256, 0, stream>>>(
                T1h, T1l, (long)NN * NN, Wh, Wl, 0L, nullptr, nullptr, out_rho,
                nullptr, sva, svb, nullptr, nullptr, u_linT,
                w_mean, b_mean, u_e, s_e2, GTt, GIt, HIt, nu, ns);
        }
        cu = nu;
    }
}